// Round 6
// baseline (6501.758 us; speedup 1.0000x reference)
//
#include <hip/hip_runtime.h>
#include <stdint.h>

constexpr int kV = 128, kE = 100, kH = 1024, kB = 64, kT = 512, kH3 = 3072;

typedef __bf16 bf16_t;
typedef __bf16 bf16x8 __attribute__((ext_vector_type(8)));
typedef float f32x4 __attribute__((ext_vector_type(4)));

// ---------------- P = emb @ Wx + b_in (+ b_rec for z,r gates) : [128][3072] f32
__global__ void k_prep_P(const float* __restrict__ emb, const float* __restrict__ Wx,
                         const float* __restrict__ b_in, const float* __restrict__ b_rec,
                         float* __restrict__ P) {
    const int n = blockIdx.x * 256 + threadIdx.x;   // 12 blocks.x * 256 = 3072
    const int v0 = blockIdx.y * 32;                 // 4 blocks.y
    float wcol[kE];
#pragma unroll
    for (int e = 0; e < kE; ++e) wcol[e] = Wx[e * kH3 + n];
    const float bias = b_in[n] + (n < 2 * kH ? b_rec[n] : 0.f);
    for (int vi = 0; vi < 32; ++vi) {
        const int v = v0 + vi;
        float acc = bias;
#pragma unroll
        for (int e = 0; e < kE; ++e) acc += emb[v * kE + e] * wcol[e];
        P[v * kH3 + n] = acc;
    }
}

// ---------------- WdT = bf16(Wd^T) : [128][1024]
__global__ void k_prep_WdT(const float* __restrict__ Wd, bf16_t* __restrict__ WdT) {
    const int i = blockIdx.x * 256 + threadIdx.x;   // 512 blocks -> 131072
    const int v = i & 127, k = i >> 7;
    WdT[v * kH + k] = (bf16_t)Wd[k * kV + v];
}

// ---------------- tokT[t][b] = tokens[b][t]
__global__ void k_prep_tokT(const int* __restrict__ tokens, int* __restrict__ tokT) {
    const int i = blockIdx.x * 256 + threadIdx.x;   // 128 blocks -> 32768
    const int b = i & 63, t = i >> 6;
    tokT[i] = tokens[b * kT + t];
}

// ---------------- persistent GRU scan, XCD-local h exchange:
// 256 WGs x 256 thr, 1 WG/CU (LDS>80KB). Physical XCD x (HW_REG_XCC_ID, r4-proven
// coverage) owns batch rows [8x,8x+8); its 32 WGs (slot via atomic claim) own
// h-cols [32s,32s+32). h: PLAIN stores -> dirty lines in the shared per-XCD L2;
// consumers: one acquire-agent fence per step (r3-proven) + plain dwordx4 loads
// (L2-hit; dirty lines survive the clean-invalidate). Flags: compiler agent
// atomics at MALL (r5-proven), relaxed store after explicit vmcnt(0).
__launch_bounds__(256, 1)
__global__ void k_scan(const int* __restrict__ tokT, const float* __restrict__ Uh,
                       const float* __restrict__ Pg, const float* __restrict__ b_rec,
                       bf16_t* __restrict__ hbuf, bf16_t* __restrict__ seq,
                       unsigned* __restrict__ flags, unsigned* __restrict__ slotCtr) {
    __shared__ float Pl[kV][104];       // [v][0:32)=z,[32:64)=r,[64:96)=hh (pads->LDS>80KB)
    __shared__ float part[4][24][100];  // [wave][row(8 used)][col 0:96) partial pre-acts
    __shared__ int s_xcd, s_slot;
    const int tid = threadIdx.x;
    const int lane = tid & 63, wave = tid >> 6;
    const int r16 = lane & 15, grp = lane >> 4;

    if (tid == 0) {
        int x;
        asm volatile("s_getreg_b32 %0, hwreg(HW_REG_XCC_ID)" : "=s"(x));
        x &= 7;
        s_xcd = x;
        s_slot = (int)(atomicAdd(&slotCtr[x], 1u) & 31u);
    }
    __syncthreads();
    const int xcd = s_xcd, slot = s_slot;
    const int c0 = slot * 32;      // this WG's h-column base
    const int g0 = xcd * 32;       // this group's flag base
    const int row8 = 8 * xcd;      // this group's batch-row base

    // stage P gather table for this WG's 96 gate columns (b_in/b_rec(z,r) folded)
    for (int idx = tid; idx < kV * 96; idx += 256) {
        const int v = idx / 96, gi = idx % 96;
        const int col = (gi >> 5) * kH + c0 + (gi & 31);
        Pl[v][gi] = Pg[v * kH3 + col];
    }
    // B-fragments: 6 output tiles x 8 K-steps for this wave's K-slice -> 192 VGPRs
    bf16x8 bf[6][8];
#pragma unroll
    for (int tile = 0; tile < 6; ++tile) {
        const int col = (tile >> 1) * kH + c0 + (tile & 1) * 16 + r16;
#pragma unroll
        for (int ks = 0; ks < 8; ++ks) {
#pragma unroll
            for (int j = 0; j < 8; ++j)
                bf[tile][ks][j] = (bf16_t)Uh[(wave * 256 + ks * 32 + grp * 8 + j) * kH3 + col];
    }
    }
    // wave0 gate-lane constants: lane -> (row = lane>>3, 4 cols at c4 = (lane&7)*4)
    const int grow = lane >> 3, c4 = (lane & 7) * 4;
    float brh4[4], hreg[4] = {0.f, 0.f, 0.f, 0.f};
#pragma unroll
    for (int i = 0; i < 4; ++i) brh4[i] = b_rec[2 * kH + c0 + c4 + i];
    const int arow = r16 & 7;                      // A-frag local row (rows 8-15 dup)
    int tokc = tokT[0 * kB + row8 + grow];
    __syncthreads();

    for (int t = 0; t < kT; ++t) {
        // ---- wait: all 32 slots of this group published step t
        if (t > 0) {
            if (lane < 8) {
                const unsigned* fp = flags + g0 + wave * 8 + lane;
                long guard = 0;
                while (__hip_atomic_load(fp, __ATOMIC_RELAXED, __HIP_MEMORY_SCOPE_AGENT)
                       < (unsigned)t) {
                    __builtin_amdgcn_s_sleep(1);
                    if (++guard > (1L << 15)) break;   // anti-hang escape
                }
            }
        }
        __syncthreads();   // joins waves; also part[] WAR hazard fence
        if (t > 0)
            __builtin_amdgcn_fence(__ATOMIC_ACQUIRE, "agent");  // L1(+clean-L2) inv

        // ---- partial matmul over this wave's K-slice (plain loads, local-L2 hits)
        f32x4 acc[6];
#pragma unroll
        for (int tile = 0; tile < 6; ++tile) acc[tile] = (f32x4){0.f, 0.f, 0.f, 0.f};
        if (t > 0) {
            const bf16_t* hprev = hbuf + (size_t)(xcd * 2 + ((t & 1) ^ 1)) * (8 * kH);
            const bf16_t* ap = hprev + arow * kH + wave * 256 + grp * 8;
            bf16x8 av[8];
#pragma unroll
            for (int ks = 0; ks < 8; ++ks)
                av[ks] = *(const bf16x8*)(ap + ks * 32);
#pragma unroll
            for (int ks = 0; ks < 8; ++ks)
#pragma unroll
                for (int tile = 0; tile < 6; ++tile)
                    acc[tile] = __builtin_amdgcn_mfma_f32_16x16x32_bf16(av[ks], bf[tile][ks],
                                                                        acc[tile], 0, 0, 0);
            if (grp < 2) {      // rows 0-7 real; write partial pre-acts
#pragma unroll
                for (int tile = 0; tile < 6; ++tile)
#pragma unroll
                    for (int q = 0; q < 4; ++q)
                        part[wave][grp * 4 + q][tile * 16 + r16] = acc[tile][q];
            }
        }
        __syncthreads();

        // ---- wave 0: reduce partials, gates, state update, stores, publish
        if (wave == 0) {
            f32x4 rz = {0.f, 0.f, 0.f, 0.f}, rr = rz, rh = rz;
            if (t > 0) {
#pragma unroll
                for (int w2 = 0; w2 < 4; ++w2) {
                    rz += *(const f32x4*)&part[w2][grow][c4];
                    rr += *(const f32x4*)&part[w2][grow][32 + c4];
                    rh += *(const f32x4*)&part[w2][grow][64 + c4];
                }
            }
            union { bf16_t h[4]; unsigned long long u; } hp;
#pragma unroll
            for (int i = 0; i < 4; ++i) {
                const float z = 1.f / (1.f + __expf(-(Pl[tokc][c4 + i] + rz[i])));
                const float r = 1.f / (1.f + __expf(-(Pl[tokc][32 + c4 + i] + rr[i])));
                float hh = Pl[tokc][64 + c4 + i] + r * (rh[i] + brh4[i]);
                hh = hh > 0.f ? hh : 0.f;
                const float hnew = z * hreg[i] + (1.f - z) * hh;
                hreg[i] = hnew;
                hp.h[i] = (bf16_t)hnew;
            }
            if (t < kT - 1) {
                bf16_t* hnext = hbuf + (size_t)(xcd * 2 + (t & 1)) * (8 * kH);
                *(unsigned long long*)(hnext + grow * kH + c0 + c4) = hp.u;  // PLAIN -> L2 dirty
                asm volatile("s_waitcnt vmcnt(0)" ::: "memory");             // h acked in L2
                if (lane == 0)
                    __hip_atomic_store(&flags[g0 + slot], (unsigned)(t + 1),
                                       __ATOMIC_RELAXED, __HIP_MEMORY_SCOPE_AGENT);
            }
            *(unsigned long long*)(seq + ((size_t)(row8 + grow) * kT + t) * kH + c0 + c4) = hp.u;
            if (t < kT - 1)
                tokc = tokT[(t + 1) * kB + row8 + grow];   // off critical path
        }
    }
}

// ---------------- logits = seq @ Wd^T' + bd : 512 WGs x 64 rows
__global__ void k_logits(const bf16_t* __restrict__ seq, const bf16_t* __restrict__ WdT,
                         const float* __restrict__ bd, float* __restrict__ out) {
    const int m0 = blockIdx.x * 64;
    const int lane = threadIdx.x & 63, wave = threadIdx.x >> 6;
    const int r16 = lane & 15, grp = lane >> 4;
    f32x4 acc[8];
#pragma unroll
    for (int n = 0; n < 8; ++n) acc[n] = (f32x4){0.f, 0.f, 0.f, 0.f};
    const bf16_t* ap = seq + (m0 + 16 * wave + r16) * kH + 8 * grp;
    const bf16_t* bp = WdT + r16 * kH + 8 * grp;
    for (int ks = 0; ks < 32; ++ks) {
        const int k0 = 32 * ks;
        bf16x8 a = *(const bf16x8*)(ap + k0);
#pragma unroll
        for (int nt = 0; nt < 8; ++nt) {
            bf16x8 b = *(const bf16x8*)(bp + nt * 16 * kH + k0);
            acc[nt] = __builtin_amdgcn_mfma_f32_16x16x32_bf16(a, b, acc[nt], 0, 0, 0);
        }
    }
#pragma unroll
    for (int nt = 0; nt < 8; ++nt) {
        const int v = 16 * nt + r16;
        const float bias = bd[v];
#pragma unroll
        for (int q = 0; q < 4; ++q) {
            const int m = m0 + 16 * wave + 4 * grp + q;
            out[m * kV + v] = acc[nt][q] + bias;
        }
    }
}

extern "C" void kernel_launch(void* const* d_in, const int* in_sizes, int n_in,
                              void* d_out, int out_size, void* d_ws, size_t ws_size,
                              hipStream_t stream) {
    const int*   tokens = (const int*)d_in[0];
    const float* emb    = (const float*)d_in[1];
    const float* Wx     = (const float*)d_in[2];
    const float* Uh     = (const float*)d_in[3];
    const float* b_in   = (const float*)d_in[4];
    const float* b_rec  = (const float*)d_in[5];
    const float* Wd     = (const float*)d_in[6];
    const float* bd     = (const float*)d_in[7];
    float* out = (float*)d_out;

    char* ws = (char*)d_ws;
    bf16_t*   seq     = (bf16_t*)ws;                    // 64*512*1024*2 = 67,108,864 B
    float*    P       = (float*)(ws + 67108864);        // 128*3072*4   =  1,572,864 B
    bf16_t*   WdT     = (bf16_t*)(ws + 68681728);       // 128*1024*2   =    262,144 B
    bf16_t*   hbuf    = (bf16_t*)(ws + 68943872);       // 8*2*8*1024*2 =    262,144 B
    unsigned* flags   = (unsigned*)(ws + 69206016);     // 256*4 = 1024 B
    unsigned* slotCtr = (unsigned*)(ws + 69207040);     // 8*4 B (memset with flags)
    int*      tokT    = (int*)(ws + 69210112);          // 32768*4      =    131,072 B

    k_prep_P<<<dim3(12, 4), 256, 0, stream>>>(emb, Wx, b_in, b_rec, P);
    k_prep_WdT<<<512, 256, 0, stream>>>(Wd, WdT);
    k_prep_tokT<<<128, 256, 0, stream>>>(tokens, tokT);
    hipMemsetAsync(flags, 0, 2048, stream);
    k_scan<<<256, 256, 0, stream>>>(tokT, Uh, P, b_rec, hbuf, seq, flags, slotCtr);
    k_logits<<<512, 256, 0, stream>>>(seq, WdT, bd, out);
}

// Round 7
// 3595.219 us; speedup vs baseline: 1.8084x; 1.8084x over previous
//
#include <hip/hip_runtime.h>
#include <stdint.h>

constexpr int kV = 128, kE = 100, kH = 1024, kB = 64, kT = 512, kH3 = 3072;

typedef __bf16 bf16_t;
typedef __bf16 bf16x8 __attribute__((ext_vector_type(8)));
typedef float f32x4 __attribute__((ext_vector_type(4)));

// ---------------- P = emb @ Wx + b_in (+ b_rec for z,r gates) : [128][3072] f32
__global__ void k_prep_P(const float* __restrict__ emb, const float* __restrict__ Wx,
                         const float* __restrict__ b_in, const float* __restrict__ b_rec,
                         float* __restrict__ P) {
    const int n = blockIdx.x * 256 + threadIdx.x;   // 12 blocks.x * 256 = 3072
    const int v0 = blockIdx.y * 32;                 // 4 blocks.y
    float wcol[kE];
#pragma unroll
    for (int e = 0; e < kE; ++e) wcol[e] = Wx[e * kH3 + n];
    const float bias = b_in[n] + (n < 2 * kH ? b_rec[n] : 0.f);
    for (int vi = 0; vi < 32; ++vi) {
        const int v = v0 + vi;
        float acc = bias;
#pragma unroll
        for (int e = 0; e < kE; ++e) acc += emb[v * kE + e] * wcol[e];
        P[v * kH3 + n] = acc;
    }
}

// ---------------- WdT = bf16(Wd^T) : [128][1024]
__global__ void k_prep_WdT(const float* __restrict__ Wd, bf16_t* __restrict__ WdT) {
    const int i = blockIdx.x * 256 + threadIdx.x;   // 512 blocks -> 131072
    const int v = i & 127, k = i >> 7;
    WdT[v * kH + k] = (bf16_t)Wd[k * kV + v];
}

// ---------------- persistent GRU scan (r5 structure + poll-storm fix):
// 256 WGs x 256 thr, group g = blockIdx>>5 owns batch rows [8g,8g+8);
// slot = blockIdx&31 owns h-cols [32s,32s+32). Wave w holds all 96 gate-cols of
// Uh for K-slice [256w,256w+256) in VGPRs; partial C reduced via LDS.
// Flags: ONE u32 per 128B line (no MALL same-line storm); only wave0's 32 lanes
// poll (one flag each, s_sleep backoff); flag release-store issued BEFORE the
// seq HBM store so vmcnt(0) covers only the 8B h-stores.
__launch_bounds__(256, 1)
__global__ void k_scan(const int* __restrict__ tokens, const float* __restrict__ Uh,
                       const float* __restrict__ Pg, const float* __restrict__ b_rec,
                       bf16_t* __restrict__ hbuf, bf16_t* __restrict__ seq,
                       unsigned* __restrict__ flags) {
    __shared__ float Pl[kV][104];       // [v][0:32)=z,[32:64)=r,[64:96)=hh (pads->LDS>80KB)
    __shared__ float part[4][24][100];  // [wave][row(8 used)][col 0:96) partial pre-acts
    const int tid = threadIdx.x;
    const int g = blockIdx.x >> 5, slot = blockIdx.x & 31;
    const int c0 = slot * 32;
    const int lane = tid & 63, wave = tid >> 6;
    const int r16 = lane & 15, grp = lane >> 4;

    // stage P gather table for this WG's 96 gate columns (b_in/b_rec(z,r) folded)
    for (int idx = tid; idx < kV * 96; idx += 256) {
        const int v = idx / 96, gi = idx % 96;
        const int col = (gi >> 5) * kH + c0 + (gi & 31);
        Pl[v][gi] = Pg[v * kH3 + col];
    }
    // B-fragments: 6 output tiles x 8 K-steps for this wave's K-slice -> 192 VGPRs
    bf16x8 bf[6][8];
#pragma unroll
    for (int tile = 0; tile < 6; ++tile) {
        const int col = (tile >> 1) * kH + c0 + (tile & 1) * 16 + r16;
#pragma unroll
        for (int ks = 0; ks < 8; ++ks) {
#pragma unroll
            for (int j = 0; j < 8; ++j)
                bf[tile][ks][j] = (bf16_t)Uh[(wave * 256 + ks * 32 + grp * 8 + j) * kH3 + col];
        }
    }
    // wave0 gate-lane constants: lane -> (row = lane>>3, 4 cols at c4 = (lane&7)*4)
    const int grow = lane >> 3, c4 = (lane & 7) * 4;
    float brh4[4], hreg[4] = {0.f, 0.f, 0.f, 0.f};
#pragma unroll
    for (int i = 0; i < 4; ++i) brh4[i] = b_rec[2 * kH + c0 + c4 + i];
    const int arow = r16 & 7;                      // A-frag local row (rows 8-15 dup)
    __syncthreads();

    for (int t = 0; t < kT; ++t) {
        // ---- wait: all 32 slots of this group published step t.
        // 32 pollers/WG, each on its OWN 128B flag line; s_sleep(8) ~0.2us backoff.
        if (t > 0 && wave == 0 && lane < 32) {
            const unsigned* fp = flags + (size_t)(g * 32 + lane) * 32;
            long guard = 0;
            while (__hip_atomic_load(fp, __ATOMIC_RELAXED, __HIP_MEMORY_SCOPE_AGENT)
                   < (unsigned)t) {
                __builtin_amdgcn_s_sleep(8);
                if (++guard > (1L << 13)) break;   // anti-hang escape
            }
        }
        __syncthreads();   // joins waves; also part[] WAR hazard fence

        // ---- partial matmul over this wave's K-slice
        f32x4 acc[6];
#pragma unroll
        for (int tile = 0; tile < 6; ++tile) acc[tile] = (f32x4){0.f, 0.f, 0.f, 0.f};
        if (t > 0) {
            const bf16_t* hprev = hbuf + (((t & 1) ^ 1) * kB + 8 * g) * kH;
            const unsigned long long* ap =
                (const unsigned long long*)(hprev + arow * kH + wave * 256 + grp * 8);
            bf16x8 av[8];
#pragma unroll
            for (int ks = 0; ks < 8; ++ks) {
                union { unsigned long long u[2]; bf16x8 v; } au;
                au.u[0] = __hip_atomic_load(ap + ks * 8, __ATOMIC_RELAXED,
                                            __HIP_MEMORY_SCOPE_AGENT);
                au.u[1] = __hip_atomic_load(ap + ks * 8 + 1, __ATOMIC_RELAXED,
                                            __HIP_MEMORY_SCOPE_AGENT);
                av[ks] = au.v;
            }
#pragma unroll
            for (int ks = 0; ks < 8; ++ks)
#pragma unroll
                for (int tile = 0; tile < 6; ++tile)
                    acc[tile] = __builtin_amdgcn_mfma_f32_16x16x32_bf16(av[ks], bf[tile][ks],
                                                                        acc[tile], 0, 0, 0);
            if (grp < 2) {      // rows 0-7 real; write partial pre-acts
#pragma unroll
                for (int tile = 0; tile < 6; ++tile)
#pragma unroll
                    for (int q = 0; q < 4; ++q)
                        part[wave][grp * 4 + q][tile * 16 + r16] = acc[tile][q];
            }
        }
        __syncthreads();

        // ---- wave 0: reduce partials, gates, state update, publish, then seq
        if (wave == 0) {
            const int tok = tokens[(8 * g + grow) * kT + t];
            f32x4 rz = {0.f, 0.f, 0.f, 0.f}, rr = rz, rh = rz;
            if (t > 0) {
#pragma unroll
                for (int w2 = 0; w2 < 4; ++w2) {
                    rz += *(const f32x4*)&part[w2][grow][c4];
                    rr += *(const f32x4*)&part[w2][grow][32 + c4];
                    rh += *(const f32x4*)&part[w2][grow][64 + c4];
                }
            }
            union { bf16_t h[4]; unsigned long long u; } hp;
#pragma unroll
            for (int i = 0; i < 4; ++i) {
                const float z = 1.f / (1.f + __expf(-(Pl[tok][c4 + i] + rz[i])));
                const float r = 1.f / (1.f + __expf(-(Pl[tok][32 + c4 + i] + rr[i])));
                float hh = Pl[tok][64 + c4 + i] + r * (rh[i] + brh4[i]);
                hh = hh > 0.f ? hh : 0.f;
                const float hnew = z * hreg[i] + (1.f - z) * hh;
                hreg[i] = hnew;
                hp.h[i] = (bf16_t)hnew;
            }
            if (t < kT - 1) {
                __hip_atomic_store((unsigned long long*)(hbuf + (((t & 1) * kB) + 8 * g + grow) * kH
                                                         + c0 + c4),
                                   hp.u, __ATOMIC_RELAXED, __HIP_MEMORY_SCOPE_AGENT);
                // release-store: implicit vmcnt(0) covers ONLY the h stores above
                if (lane == 0)
                    __hip_atomic_store(flags + (size_t)(g * 32 + slot) * 32, (unsigned)(t + 1),
                                       __ATOMIC_RELEASE, __HIP_MEMORY_SCOPE_AGENT);
            }
            // seq HBM store AFTER publish: off the inter-WG critical path
            *(unsigned long long*)(seq + ((size_t)(8 * g + grow) * kT + t) * kH + c0 + c4) = hp.u;
        }
    }
}

// ---------------- logits = seq @ Wd^T' + bd : 512 WGs x 64 rows
__global__ void k_logits(const bf16_t* __restrict__ seq, const bf16_t* __restrict__ WdT,
                         const float* __restrict__ bd, float* __restrict__ out) {
    const int m0 = blockIdx.x * 64;
    const int lane = threadIdx.x & 63, wave = threadIdx.x >> 6;
    const int r16 = lane & 15, grp = lane >> 4;
    f32x4 acc[8];
#pragma unroll
    for (int n = 0; n < 8; ++n) acc[n] = (f32x4){0.f, 0.f, 0.f, 0.f};
    const bf16_t* ap = seq + (m0 + 16 * wave + r16) * kH + 8 * grp;
    const bf16_t* bp = WdT + r16 * kH + 8 * grp;
    for (int ks = 0; ks < 32; ++ks) {
        const int k0 = 32 * ks;
        bf16x8 a = *(const bf16x8*)(ap + k0);
#pragma unroll
        for (int nt = 0; nt < 8; ++nt) {
            bf16x8 b = *(const bf16x8*)(bp + nt * 16 * kH + k0);
            acc[nt] = __builtin_amdgcn_mfma_f32_16x16x32_bf16(a, b, acc[nt], 0, 0, 0);
        }
    }
#pragma unroll
    for (int nt = 0; nt < 8; ++nt) {
        const int v = 16 * nt + r16;
        const float bias = bd[v];
#pragma unroll
        for (int q = 0; q < 4; ++q) {
            const int m = m0 + 16 * wave + 4 * grp + q;
            out[m * kV + v] = acc[nt][q] + bias;
        }
    }
}

extern "C" void kernel_launch(void* const* d_in, const int* in_sizes, int n_in,
                              void* d_out, int out_size, void* d_ws, size_t ws_size,
                              hipStream_t stream) {
    const int*   tokens = (const int*)d_in[0];
    const float* emb    = (const float*)d_in[1];
    const float* Wx     = (const float*)d_in[2];
    const float* Uh     = (const float*)d_in[3];
    const float* b_in   = (const float*)d_in[4];
    const float* b_rec  = (const float*)d_in[5];
    const float* Wd     = (const float*)d_in[6];
    const float* bd     = (const float*)d_in[7];
    float* out = (float*)d_out;

    char* ws = (char*)d_ws;
    bf16_t*   seq   = (bf16_t*)ws;                    // 64*512*1024*2 = 67,108,864 B
    float*    P     = (float*)(ws + 67108864);        // 128*3072*4   =  1,572,864 B
    bf16_t*   WdT   = (bf16_t*)(ws + 68681728);       // 128*1024*2   =    262,144 B
    bf16_t*   hbuf  = (bf16_t*)(ws + 68943872);       // 2*64*1024*2  =    262,144 B
    unsigned* flags = (unsigned*)(ws + 69206016);     // 256 flags x 128B = 32,768 B

    k_prep_P<<<dim3(12, 4), 256, 0, stream>>>(emb, Wx, b_in, b_rec, P);
    k_prep_WdT<<<512, 256, 0, stream>>>(Wd, WdT);
    hipMemsetAsync(flags, 0, 32768, stream);
    k_scan<<<256, 256, 0, stream>>>(tokens, Uh, P, b_rec, hbuf, seq, flags);
    k_logits<<<512, 256, 0, stream>>>(seq, WdT, bd, out);
}

// Round 8
// 3522.003 us; speedup vs baseline: 1.8460x; 1.0208x over previous
//
#include <hip/hip_runtime.h>
#include <stdint.h>

constexpr int kV = 128, kE = 100, kH = 1024, kB = 64, kT = 512, kH3 = 3072;

typedef __bf16 bf16_t;
typedef __bf16 bf16x8 __attribute__((ext_vector_type(8)));
typedef float f32x4 __attribute__((ext_vector_type(4)));

// ---------------- P = emb @ Wx + b_in (+ b_rec for z,r gates) : [128][3072] f32
__global__ void k_prep_P(const float* __restrict__ emb, const float* __restrict__ Wx,
                         const float* __restrict__ b_in, const float* __restrict__ b_rec,
                         float* __restrict__ P) {
    const int n = blockIdx.x * 256 + threadIdx.x;   // 12 blocks.x * 256 = 3072
    const int v0 = blockIdx.y * 32;                 // 4 blocks.y
    float wcol[kE];
#pragma unroll
    for (int e = 0; e < kE; ++e) wcol[e] = Wx[e * kH3 + n];
    const float bias = b_in[n] + (n < 2 * kH ? b_rec[n] : 0.f);
    for (int vi = 0; vi < 32; ++vi) {
        const int v = v0 + vi;
        float acc = bias;
#pragma unroll
        for (int e = 0; e < kE; ++e) acc += emb[v * kE + e] * wcol[e];
        P[v * kH3 + n] = acc;
    }
}

// ---------------- WdT = bf16(Wd^T) : [128][1024]
__global__ void k_prep_WdT(const float* __restrict__ Wd, bf16_t* __restrict__ WdT) {
    const int i = blockIdx.x * 256 + threadIdx.x;   // 512 blocks -> 131072
    const int v = i & 127, k = i >> 7;
    WdT[v * kH + k] = (bf16_t)Wd[k * kV + v];
}

// ---------------- persistent GRU scan, dataflow pipeline:
// 256 WGs x 576 thr (8 K-waves + 1 gate wave). group g = blockIdx>>5 owns batch
// rows [8g,8g+8); slot = blockIdx&31 owns h-cols [32s,32s+32).
// K-wave w: K-slice [128w,128w+128) -> needs producers (slots) [4w,4w+4) ONLY;
// bf[6][4] = 96 VGPRs stays register-resident (r7's bf[6][8]=192 spilled at
// VGPR_Count 136). One syncthreads/step (part[] double-buffered); gate wave
// reduces partials, computes gates, publishes h (relaxed MALL) + flag (release).
// Depth-2 h buffer safe: WG writes h[t+2] over h[t] only after its 8 waves'
// polls (union = all 32 slots) confirm flag >= t+1 => everyone consumed h[t].
__launch_bounds__(576, 1)
__global__ void k_scan(const int* __restrict__ tokens, const float* __restrict__ Uh,
                       const float* __restrict__ Pg, const float* __restrict__ b_rec,
                       bf16_t* __restrict__ hbuf, bf16_t* __restrict__ seq,
                       unsigned* __restrict__ flags) {
    __shared__ float Pl[kV][104];          // [v][0:32)=z,[32:64)=r,[64:96)=hh
    __shared__ float part[2][8][8][104];   // [parity][kwave][row][gatecol 0:96)
    const int tid = threadIdx.x;
    const int g = blockIdx.x >> 5, slot = blockIdx.x & 31;
    const int c0 = slot * 32;
    const int lane = tid & 63, wave = tid >> 6;    // 0..8
    const int r16 = lane & 15, grp = lane >> 4;

    // stage P gather table for this WG's 96 gate columns (b_in/b_rec(z,r) folded)
    for (int idx = tid; idx < kV * 96; idx += 576) {
        const int v = idx / 96, gi = idx % 96;
        const int col = (gi >> 5) * kH + c0 + (gi & 31);
        Pl[v][gi] = Pg[v * kH3 + col];
    }
    // K-wave B-fragments: 6 tiles x 4 K-steps -> 96 VGPRs, resident all 512 steps
    bf16x8 bf[6][4];
    if (wave < 8) {
#pragma unroll
        for (int tile = 0; tile < 6; ++tile) {
            const int col = (tile >> 1) * kH + c0 + (tile & 1) * 16 + r16;
#pragma unroll
            for (int ks = 0; ks < 4; ++ks)
#pragma unroll
                for (int j = 0; j < 8; ++j)
                    bf[tile][ks][j] = (bf16_t)Uh[(wave * 128 + ks * 32 + grp * 8 + j) * kH3 + col];
        }
    }
    // gate-wave lane constants: row = lane>>3, 4 cols at c4 = (lane&7)*4
    const int grow = lane >> 3, c4 = (lane & 7) * 4;
    float brh4[4], hreg[4] = {0.f, 0.f, 0.f, 0.f};
#pragma unroll
    for (int i = 0; i < 4; ++i) brh4[i] = b_rec[2 * kH + c0 + c4 + i];
    int tokc = tokens[(8 * g + grow) * kT + 0];
    const int arow = r16 & 7;                      // A-frag row (rows 8-15 dup)
    __syncthreads();

    for (int t = 0; t < kT; ++t) {
        if (wave < 8 && t > 0) {
            // ---- wait ONLY for this wave's 4 producer slots
            if (lane < 4) {
                const unsigned* fp = flags + (size_t)(g * 32 + wave * 4 + lane) * 32;
                long guard = 0;
                while (__hip_atomic_load(fp, __ATOMIC_RELAXED, __HIP_MEMORY_SCOPE_AGENT)
                       < (unsigned)t) {
                    __builtin_amdgcn_s_sleep(1);
                    if (++guard > (1L << 14)) break;   // anti-hang escape
                }
            }
            // ---- load A-slice (MALL-fresh via agent atomics), partial matmul
            f32x4 acc[6];
#pragma unroll
            for (int tl = 0; tl < 6; ++tl) acc[tl] = (f32x4){0.f, 0.f, 0.f, 0.f};
            const bf16_t* hprev = hbuf + (((t & 1) ^ 1) * kB + 8 * g) * kH;
            const unsigned long long* ap =
                (const unsigned long long*)(hprev + arow * kH + wave * 128 + grp * 8);
            bf16x8 av[4];
#pragma unroll
            for (int ks = 0; ks < 4; ++ks) {
                union { unsigned long long u[2]; bf16x8 v; } au;
                au.u[0] = __hip_atomic_load(ap + ks * 8, __ATOMIC_RELAXED,
                                            __HIP_MEMORY_SCOPE_AGENT);
                au.u[1] = __hip_atomic_load(ap + ks * 8 + 1, __ATOMIC_RELAXED,
                                            __HIP_MEMORY_SCOPE_AGENT);
                av[ks] = au.v;
            }
#pragma unroll
            for (int ks = 0; ks < 4; ++ks)
#pragma unroll
                for (int tl = 0; tl < 6; ++tl)
                    acc[tl] = __builtin_amdgcn_mfma_f32_16x16x32_bf16(av[ks], bf[tl][ks],
                                                                      acc[tl], 0, 0, 0);
            if (grp < 2) {      // rows 0-7 real
#pragma unroll
                for (int tl = 0; tl < 6; ++tl)
#pragma unroll
                    for (int q = 0; q < 4; ++q)
                        part[t & 1][wave][grp * 4 + q][tl * 16 + r16] = acc[tl][q];
            }
        }
        __syncthreads();   // K-waves hand partials to gate wave

        // ---- gate wave: reduce 8 partials, gates, publish; K-waves race ahead
        if (wave == 8) {
            f32x4 rz = {0.f, 0.f, 0.f, 0.f}, rr = rz, rh = rz;
            if (t > 0) {
#pragma unroll
                for (int w2 = 0; w2 < 8; ++w2) {
                    rz += *(const f32x4*)&part[t & 1][w2][grow][c4];
                    rr += *(const f32x4*)&part[t & 1][w2][grow][32 + c4];
                    rh += *(const f32x4*)&part[t & 1][w2][grow][64 + c4];
                }
            }
            union { bf16_t h[4]; unsigned long long u; } hp;
#pragma unroll
            for (int i = 0; i < 4; ++i) {
                const float z = 1.f / (1.f + __expf(-(Pl[tokc][c4 + i] + rz[i])));
                const float r = 1.f / (1.f + __expf(-(Pl[tokc][32 + c4 + i] + rr[i])));
                float hh = Pl[tokc][64 + c4 + i] + r * (rh[i] + brh4[i]);
                hh = hh > 0.f ? hh : 0.f;
                const float hnew = z * hreg[i] + (1.f - z) * hh;
                hreg[i] = hnew;
                hp.h[i] = (bf16_t)hnew;
            }
            if (t < kT - 1) {
                __hip_atomic_store((unsigned long long*)(hbuf + (((t & 1) * kB) + 8 * g + grow) * kH
                                                         + c0 + c4),
                                   hp.u, __ATOMIC_RELAXED, __HIP_MEMORY_SCOPE_AGENT);
                // release: wave-level vmcnt drain covers all 64 lanes' h stores
                if (lane == 0)
                    __hip_atomic_store(flags + (size_t)(g * 32 + slot) * 32, (unsigned)(t + 1),
                                       __ATOMIC_RELEASE, __HIP_MEMORY_SCOPE_AGENT);
            }
            // seq HBM store + token prefetch: off the inter-WG critical path
            *(unsigned long long*)(seq + ((size_t)(8 * g + grow) * kT + t) * kH + c0 + c4) = hp.u;
            if (t < kT - 1) tokc = tokens[(8 * g + grow) * kT + t + 1];
        }
    }
}

// ---------------- logits = seq @ Wd^T' + bd : 512 WGs x 64 rows
__global__ void k_logits(const bf16_t* __restrict__ seq, const bf16_t* __restrict__ WdT,
                         const float* __restrict__ bd, float* __restrict__ out) {
    const int m0 = blockIdx.x * 64;
    const int lane = threadIdx.x & 63, wave = threadIdx.x >> 6;
    const int r16 = lane & 15, grp = lane >> 4;
    f32x4 acc[8];
#pragma unroll
    for (int n = 0; n < 8; ++n) acc[n] = (f32x4){0.f, 0.f, 0.f, 0.f};
    const bf16_t* ap = seq + (m0 + 16 * wave + r16) * kH + 8 * grp;
    const bf16_t* bp = WdT + r16 * kH + 8 * grp;
    for (int ks = 0; ks < 32; ++ks) {
        const int k0 = 32 * ks;
        bf16x8 a = *(const bf16x8*)(ap + k0);
#pragma unroll
        for (int nt = 0; nt < 8; ++nt) {
            bf16x8 b = *(const bf16x8*)(bp + nt * 16 * kH + k0);
            acc[nt] = __builtin_amdgcn_mfma_f32_16x16x32_bf16(a, b, acc[nt], 0, 0, 0);
        }
    }
#pragma unroll
    for (int nt = 0; nt < 8; ++nt) {
        const int v = 16 * nt + r16;
        const float bias = bd[v];
#pragma unroll
        for (int q = 0; q < 4; ++q) {
            const int m = m0 + 16 * wave + 4 * grp + q;
            out[m * kV + v] = acc[nt][q] + bias;
        }
    }
}

extern "C" void kernel_launch(void* const* d_in, const int* in_sizes, int n_in,
                              void* d_out, int out_size, void* d_ws, size_t ws_size,
                              hipStream_t stream) {
    const int*   tokens = (const int*)d_in[0];
    const float* emb    = (const float*)d_in[1];
    const float* Wx     = (const float*)d_in[2];
    const float* Uh     = (const float*)d_in[3];
    const float* b_in   = (const float*)d_in[4];
    const float* b_rec  = (const float*)d_in[5];
    const float* Wd     = (const float*)d_in[6];
    const float* bd     = (const float*)d_in[7];
    float* out = (float*)d_out;

    char* ws = (char*)d_ws;
    bf16_t*   seq   = (bf16_t*)ws;                    // 64*512*1024*2 = 67,108,864 B
    float*    P     = (float*)(ws + 67108864);        // 128*3072*4   =  1,572,864 B
    bf16_t*   WdT   = (bf16_t*)(ws + 68681728);       // 128*1024*2   =    262,144 B
    bf16_t*   hbuf  = (bf16_t*)(ws + 68943872);       // 2*64*1024*2  =    262,144 B
    unsigned* flags = (unsigned*)(ws + 69206016);     // 256 flags x 128B = 32,768 B

    k_prep_P<<<dim3(12, 4), 256, 0, stream>>>(emb, Wx, b_in, b_rec, P);
    k_prep_WdT<<<512, 256, 0, stream>>>(Wd, WdT);
    hipMemsetAsync(flags, 0, 32768, stream);
    k_scan<<<256, 576, 0, stream>>>(tokens, Uh, P, b_rec, hbuf, seq, flags);
    k_logits<<<512, 256, 0, stream>>>(seq, WdT, bd, out);
}

// Round 11
// 2658.092 us; speedup vs baseline: 2.4460x; 1.3250x over previous
//
#include <hip/hip_runtime.h>
#include <stdint.h>

constexpr int kV = 128, kE = 100, kH = 1024, kB = 64, kT = 512, kH3 = 3072;

typedef __bf16 bf16_t;
typedef __bf16 bf16x8 __attribute__((ext_vector_type(8)));
typedef float f32x4 __attribute__((ext_vector_type(4)));
typedef unsigned int u32;
typedef unsigned long long u64;

// ---------------- P = emb @ Wx + b_in (+ b_rec for z,r gates) : [128][3072] f32
__global__ void k_prep_P(const float* __restrict__ emb, const float* __restrict__ Wx,
                         const float* __restrict__ b_in, const float* __restrict__ b_rec,
                         float* __restrict__ P) {
    const int n = blockIdx.x * 256 + threadIdx.x;   // 12 blocks.x * 256 = 3072
    const int v0 = blockIdx.y * 32;                 // 4 blocks.y
    float wcol[kE];
#pragma unroll
    for (int e = 0; e < kE; ++e) wcol[e] = Wx[e * kH3 + n];
    const float bias = b_in[n] + (n < 2 * kH ? b_rec[n] : 0.f);
    for (int vi = 0; vi < 32; ++vi) {
        const int v = v0 + vi;
        float acc = bias;
#pragma unroll
        for (int e = 0; e < kE; ++e) acc += emb[v * kE + e] * wcol[e];
        P[v * kH3 + n] = acc;
    }
}

// ---------------- WdT = bf16(Wd^T) : [128][1024]
__global__ void k_prep_WdT(const float* __restrict__ Wd, bf16_t* __restrict__ WdT) {
    const int i = blockIdx.x * 256 + threadIdx.x;   // 512 blocks -> 131072
    const int v = i & 127, k = i >> 7;
    WdT[v * kH + k] = (bf16_t)Wd[k * kV + v];
}

// ---------------- persistent GRU scan (r8-green substrate, gate phase 8x parallel):
// 256 WGs x 512 thr (8 waves). group g = blockIdx>>5 owns batch rows [8g,8g+8);
// slot = blockIdx&31 owns h-cols [32s,32s+32). Wave w: (a) K-phase, K-slice
// [128w,128w+128) -> polls its 4 producer slots x 8 rows (32 flags, 32 lanes,
// each flag on its own 128B line), loads h via relaxed-AGENT u64 atomics
// (r8-proven), MFMAs into part[]; (b) after the single per-step sync, gate
// phase for row w: reduce partials, gates, store row-h (relaxed-AGENT u64),
// own-wave vmcnt(0) drain, publish (slot,row) flag relaxed (r6-proven publish).
// No release atomics, no serial gate wave, one syncthreads per step.
// WAR depth-2 safety: the sync joins all 8 waves AFTER their polls
// (union = all 32 slots at flag >= t), so a wave's h[t] store (over h[t-2])
// happens only after every WG completed its A-loads of h[t-2]. Flags monotone
// => no deadlock. Flags memset per launch.
__launch_bounds__(512, 1)
__global__ void k_scan(const int* __restrict__ tokens, const float* __restrict__ Uh,
                       const float* __restrict__ Pg, const float* __restrict__ b_rec,
                       bf16_t* __restrict__ hbuf, bf16_t* __restrict__ seq,
                       unsigned* __restrict__ flags) {
    __shared__ float Pl[kV][104];          // [v][0:32)=z,[32:64)=r,[64:96)=hh
    __shared__ float part[2][8][8][104];   // [parity][kwave][row][gatecol 0:96)
    const int tid = threadIdx.x;
    const int g = blockIdx.x >> 5, slot = blockIdx.x & 31;
    const int c0 = slot * 32;
    const int lane = tid & 63, wave = tid >> 6;    // 0..7
    const int r16 = lane & 15, grp = lane >> 4;

    // stage P gather table for this WG's 96 gate columns (b_in/b_rec(z,r) folded)
    for (int idx = tid; idx < kV * 96; idx += 512) {
        const int v = idx / 96, gi = idx % 96;
        const int col = (gi >> 5) * kH + c0 + (gi & 31);
        Pl[v][gi] = Pg[v * kH3 + col];
    }
    // B-fragments: 6 tiles x 4 K-steps for this wave's K-slice, register-resident
    bf16x8 bf[6][4];
#pragma unroll
    for (int tile = 0; tile < 6; ++tile) {
        const int col = (tile >> 1) * kH + c0 + (tile & 1) * 16 + r16;
#pragma unroll
        for (int ks = 0; ks < 4; ++ks)
#pragma unroll
            for (int j = 0; j < 8; ++j)
                bf[tile][ks][j] = (bf16_t)Uh[(wave * 128 + ks * 32 + grp * 8 + j) * kH3 + col];
    }
    // gate-phase constants: this wave owns batch row (8g + wave); lanes 0-7
    // each handle 4 cols at c4.
    const int c4 = (lane & 7) * 4;
    const int myrow = 8 * g + wave;
    float brh4[4], hreg[4] = {0.f, 0.f, 0.f, 0.f};
#pragma unroll
    for (int i = 0; i < 4; ++i) brh4[i] = b_rec[2 * kH + c0 + c4 + i];
    int tokc = tokens[(size_t)myrow * kT + 0];
    const int arow = r16 & 7;                      // A-frag row (rows 8-15 dup)
    __syncthreads();

    for (int t = 0; t < kT; ++t) {
        if (t > 0) {
            // ---- poll this wave's 4 producer slots x 8 rows (32 flags, 1/lane)
            if (lane < 32) {
                const unsigned* fp = flags +
                    (((size_t)g * 32 + (wave * 4 + (lane >> 3))) * 8 + (lane & 7)) * 32;
                long guard = 0;
                while (__hip_atomic_load(fp, __ATOMIC_RELAXED, __HIP_MEMORY_SCOPE_AGENT)
                       < (unsigned)t) {
                    __builtin_amdgcn_s_sleep(1);
                    if (++guard > (1L << 15)) break;   // anti-hang escape
                }
            }
            // ---- load A-slice (relaxed-AGENT u64, r8-proven), partial matmul
            f32x4 acc[6];
#pragma unroll
            for (int tl = 0; tl < 6; ++tl) acc[tl] = (f32x4){0.f, 0.f, 0.f, 0.f};
            const bf16_t* hprev = hbuf + (((t & 1) ^ 1) * kB + 8 * g) * kH;
            const u64* ap = (const u64*)(hprev + arow * kH + wave * 128 + grp * 8);
            bf16x8 av[4];
#pragma unroll
            for (int ks = 0; ks < 4; ++ks) {
                union { u64 u[2]; bf16x8 v; } au;
                au.u[0] = __hip_atomic_load(ap + ks * 8, __ATOMIC_RELAXED,
                                            __HIP_MEMORY_SCOPE_AGENT);
                au.u[1] = __hip_atomic_load(ap + ks * 8 + 1, __ATOMIC_RELAXED,
                                            __HIP_MEMORY_SCOPE_AGENT);
                av[ks] = au.v;
            }
#pragma unroll
            for (int ks = 0; ks < 4; ++ks)
#pragma unroll
                for (int tl = 0; tl < 6; ++tl)
                    acc[tl] = __builtin_amdgcn_mfma_f32_16x16x32_bf16(av[ks], bf[tl][ks],
                                                                      acc[tl], 0, 0, 0);
            if (grp < 2) {      // rows 0-7 real
#pragma unroll
                for (int tl = 0; tl < 6; ++tl)
#pragma unroll
                    for (int q = 0; q < 4; ++q)
                        part[t & 1][wave][grp * 4 + q][tl * 16 + r16] = acc[tl][q];
            }
        }
        __syncthreads();   // single per-step sync: partials ready, polls joined

        // ---- gate phase (all 8 waves in parallel; wave w owns row w, lanes 0-7)
        f32x4 rz = {0.f, 0.f, 0.f, 0.f}, rr = rz, rh = rz;
        if (t > 0) {
#pragma unroll
            for (int w2 = 0; w2 < 8; ++w2) {
                rz += *(const f32x4*)&part[t & 1][w2][wave][c4];
                rr += *(const f32x4*)&part[t & 1][w2][wave][32 + c4];
                rh += *(const f32x4*)&part[t & 1][w2][wave][64 + c4];
            }
        }
        unsigned short hs[4];
#pragma unroll
        for (int i = 0; i < 4; ++i) {
            const float z = 1.f / (1.f + __expf(-(Pl[tokc][c4 + i] + rz[i])));
            const float r = 1.f / (1.f + __expf(-(Pl[tokc][32 + c4 + i] + rr[i])));
            float hh = Pl[tokc][64 + c4 + i] + r * (rh[i] + brh4[i]);
            hh = hh > 0.f ? hh : 0.f;
            const float hnew = z * hreg[i] + (1.f - z) * hh;
            hreg[i] = hnew;
            union { bf16_t h; unsigned short s; } cv; cv.h = (bf16_t)hnew;
            hs[i] = cv.s;
        }
        const u64 hp = (u64)hs[0] | ((u64)hs[1] << 16) | ((u64)hs[2] << 32) | ((u64)hs[3] << 48);
        if (t < kT - 1) {
            if (lane < 8)
                __hip_atomic_store((u64*)(hbuf + (((t & 1) * kB) + myrow) * kH + c0 + c4),
                                   hp, __ATOMIC_RELAXED, __HIP_MEMORY_SCOPE_AGENT);
            // own-wave drain: the 8 lanes' h stores are MALL-acked, then publish
            asm volatile("s_waitcnt vmcnt(0)" ::: "memory");
            if (lane == 0)
                __hip_atomic_store(flags + (((size_t)g * 32 + slot) * 8 + wave) * 32,
                                   (unsigned)(t + 1),
                                   __ATOMIC_RELAXED, __HIP_MEMORY_SCOPE_AGENT);
        }
        // seq HBM store + token prefetch: off the inter-WG critical path
        if (lane < 8)
            *(u64*)(seq + ((size_t)myrow * kT + t) * kH + c0 + c4) = hp;
        if (t < kT - 1) tokc = tokens[(size_t)myrow * kT + t + 1];
    }
}

// ---------------- logits = seq @ Wd^T' + bd : 512 WGs x 64 rows
__global__ void k_logits(const bf16_t* __restrict__ seq, const bf16_t* __restrict__ WdT,
                         const float* __restrict__ bd, float* __restrict__ out) {
    const int m0 = blockIdx.x * 64;
    const int lane = threadIdx.x & 63, wave = threadIdx.x >> 6;
    const int r16 = lane & 15, grp = lane >> 4;
    f32x4 acc[8];
#pragma unroll
    for (int n = 0; n < 8; ++n) acc[n] = (f32x4){0.f, 0.f, 0.f, 0.f};
    const bf16_t* ap = seq + (m0 + 16 * wave + r16) * kH + 8 * grp;
    const bf16_t* bp = WdT + r16 * kH + 8 * grp;
    for (int ks = 0; ks < 32; ++ks) {
        const int k0 = 32 * ks;
        bf16x8 a = *(const bf16x8*)(ap + k0);
#pragma unroll
        for (int nt = 0; nt < 8; ++nt) {
            bf16x8 b = *(const bf16x8*)(bp + nt * 16 * kH + k0);
            acc[nt] = __builtin_amdgcn_mfma_f32_16x16x32_bf16(a, b, acc[nt], 0, 0, 0);
        }
    }
#pragma unroll
    for (int nt = 0; nt < 8; ++nt) {
        const int v = 16 * nt + r16;
        const float bias = bd[v];
#pragma unroll
        for (int q = 0; q < 4; ++q) {
            const int m = m0 + 16 * wave + 4 * grp + q;
            out[m * kV + v] = acc[nt][q] + bias;
        }
    }
}

extern "C" void kernel_launch(void* const* d_in, const int* in_sizes, int n_in,
                              void* d_out, int out_size, void* d_ws, size_t ws_size,
                              hipStream_t stream) {
    const int*   tokens = (const int*)d_in[0];
    const float* emb    = (const float*)d_in[1];
    const float* Wx     = (const float*)d_in[2];
    const float* Uh     = (const float*)d_in[3];
    const float* b_in   = (const float*)d_in[4];
    const float* b_rec  = (const float*)d_in[5];
    const float* Wd     = (const float*)d_in[6];
    const float* bd     = (const float*)d_in[7];
    float* out = (float*)d_out;

    char* ws = (char*)d_ws;
    bf16_t*   seq   = (bf16_t*)ws;                    // 64*512*1024*2 = 67,108,864 B
    float*    P     = (float*)(ws + 67108864);        // 128*3072*4   =  1,572,864 B
    bf16_t*   WdT   = (bf16_t*)(ws + 68681728);       // 128*1024*2   =    262,144 B
    bf16_t*   hbuf  = (bf16_t*)(ws + 68943872);       // 2*64*1024*2  =    262,144 B
    unsigned* flags = (unsigned*)(ws + 69206016);     // 2048 flags x 128 B = 262,144 B

    k_prep_P<<<dim3(12, 4), 256, 0, stream>>>(emb, Wx, b_in, b_rec, P);
    k_prep_WdT<<<512, 256, 0, stream>>>(Wd, WdT);
    hipMemsetAsync(flags, 0, 262144, stream);
    k_scan<<<256, 512, 0, stream>>>(tokens, Uh, P, b_rec, hbuf, seq, flags);
    k_logits<<<512, 256, 0, stream>>>(seq, WdT, bd, out);
}